// Round 5
// baseline (319.212 us; speedup 1.0000x reference)
//
#include <hip/hip_runtime.h>
#include <type_traits>

#define S_LEN 2048
#define BATCH 2
#define EDIM  2048
#define NH    16
#define NKV   4
#define HDIM  128
#define QKVD  3072
// ATT_SCALE * log2(e): folded into Q at conv_rope time -> scores in log2 domain
#define QSCALE 0.12751579107188777f

typedef __attribute__((ext_vector_type(8))) short short8;
typedef __attribute__((ext_vector_type(4))) float f32x4;

__device__ __forceinline__ ushort f2bf(float f) {
  union { float f; unsigned u; } un; un.f = f;
  unsigned u = un.u + 0x7fffu + ((un.u >> 16) & 1u);
  return (ushort)(u >> 16);
}
__device__ __forceinline__ float bf2f(ushort h) {
  union { unsigned u; float f; } un; un.u = ((unsigned)h) << 16;
  return un.f;
}

__device__ __forceinline__ void load_lds16(const void* g, void* l) {
  __builtin_amdgcn_global_load_lds((const __attribute__((address_space(1))) void*)g,
                                   (__attribute__((address_space(3))) void*)l,
                                   16, 0, 0);
}

// ---------------- elementwise f32 -> bf16 cast ----------------
__global__ __launch_bounds__(256) void cast_bf16(const float* __restrict__ src,
                                                 ushort* __restrict__ dst, int n4) {
  int i = blockIdx.x * 256 + threadIdx.x;
  if (i >= n4) return;
  float4 v = ((const float4*)src)[i];
  ushort4 o;
  o.x = f2bf(v.x); o.y = f2bf(v.y); o.z = f2bf(v.z); o.w = f2bf(v.w);
  ((ushort4*)dst)[i] = o;
}

// ---------------- RoPE cos/sin table: [S][64] ----------------
__global__ __launch_bounds__(256) void rope_table(float* __restrict__ cosT,
                                                  float* __restrict__ sinT) {
  int i = blockIdx.x * 256 + threadIdx.x;   // S*64 total
  int s = i >> 6, d = i & 63;
  float inv = expf(-(float)d * 0.14391156831212787f);   // 10000^(-d/64)
  float f = (float)s * inv;
  float sv, cv;
  sincosf(f, &sv, &cv);
  cosT[i] = cv;
  sinT[i] = sv;
}

// ---------------- bf16 NT GEMM: C = A * Bt^T + bias; OBF: write bf16 else f32 ----------------
template <bool OBF>
__global__ __launch_bounds__(256) void gemm_bt(
    const ushort* __restrict__ A, const ushort* __restrict__ Bt,
    const float* __restrict__ bias, void* __restrict__ Cv,
    int M, int N, int K) {
  __shared__ __align__(16) ushort As[128 * 32];
  __shared__ __align__(16) ushort Bs[128 * 32];
  const int tid = threadIdx.x;
  const int wid = tid >> 6, lane = tid & 63;
  const int l15 = lane & 15, lg = lane >> 4;
  const int m0 = blockIdx.x * 128, n0 = blockIdx.y * 128;
  const int wr = (wid >> 1) * 64, wc = (wid & 1) * 64;
  f32x4 acc[4][4] = {};

  for (int k0 = 0; k0 < K; k0 += 32) {
#pragma unroll
    for (int j = 0; j < 2; ++j) {
      const int c = j * 256 + wid * 64 + lane;           // chunk id (16B each)
      load_lds16(A + (size_t)(m0 + (c >> 2)) * K + k0 + (c & 3) * 8,
                 As + (j * 256 + wid * 64) * 8);
      load_lds16(Bt + (size_t)(n0 + (c >> 2)) * K + k0 + (c & 3) * 8,
                 Bs + (j * 256 + wid * 64) * 8);
    }
    __syncthreads();
    short8 af[4], bf[4];
#pragma unroll
    for (int i = 0; i < 4; i++) {
      af[i] = *(const short8*)&As[(wr + i * 16 + l15) * 32 + lg * 8];
      bf[i] = *(const short8*)&Bs[(wc + i * 16 + l15) * 32 + lg * 8];
    }
#pragma unroll
    for (int mi = 0; mi < 4; mi++)
#pragma unroll
      for (int ni = 0; ni < 4; ni++)
        acc[mi][ni] = __builtin_amdgcn_mfma_f32_16x16x32_bf16(af[mi], bf[ni], acc[mi][ni], 0, 0, 0);
    __syncthreads();
  }

#pragma unroll
  for (int mi = 0; mi < 4; mi++) {
#pragma unroll
    for (int ni = 0; ni < 4; ni++) {
      const int col = n0 + wc + ni * 16 + l15;
      const float bv = bias[col];
#pragma unroll
      for (int r = 0; r < 4; r++) {
        const int row = m0 + wr + mi * 16 + lg * 4 + r;
        if constexpr (OBF)
          ((ushort*)Cv)[(size_t)row * N + col] = f2bf(acc[mi][ni][r] + bv);
        else
          ((float*)Cv)[(size_t)row * N + col] = acc[mi][ni][r] + bv;
      }
    }
  }
}

// ---------------- causal depthwise conv(K=4) + bias + RoPE -> Q/K/V bf16 ----------------
// qkv is bf16 now. Qo is pre-scaled by QSCALE (attn works in log2 domain).
__global__ __launch_bounds__(256) void conv_rope(
    const ushort* __restrict__ qkv, const float* __restrict__ cw,
    const float* __restrict__ cb, const float* __restrict__ cosT,
    const float* __restrict__ sinT, ushort* __restrict__ Qo,
    ushort* __restrict__ Ko, ushort* __restrict__ Vo) {
  const int token = blockIdx.x;            // b*S + s
  const int s = token & (S_LEN - 1);
  const int p = blockIdx.y * 256 + threadIdx.x;   // 0..1535

  auto conv1 = [&](int c) -> float {
    float a = cb[c];
#pragma unroll
    for (int j = 0; j < 4; j++) {
      int ss = s - 3 + j;
      if (ss >= 0) a += bf2f(qkv[(size_t)(token - 3 + j) * QKVD + c]) * cw[c * 4 + j];
    }
    return a;
  };

  if (p < 1024) {                 // Q heads, RoPE pair (d, d+64); pre-scaled
    int h = p >> 6, d = p & 63;
    int c1 = h * 128 + d;
    float x1 = conv1(c1), x2 = conv1(c1 + 64);
    float co = cosT[s * 64 + d], si = sinT[s * 64 + d];
    size_t base = ((size_t)token * NH + h) * HDIM + d;
    Qo[base]      = f2bf((x1 * co - x2 * si) * QSCALE);
    Qo[base + 64] = f2bf((x2 * co + x1 * si) * QSCALE);
  } else if (p < 1280) {          // K heads, RoPE pair
    int idx = p - 1024;
    int h = idx >> 6, d = idx & 63;
    int c1 = 2048 + h * 128 + d;
    float x1 = conv1(c1), x2 = conv1(c1 + 64);
    float co = cosT[s * 64 + d], si = sinT[s * 64 + d];
    size_t base = ((size_t)token * NKV + h) * HDIM + d;
    Ko[base]      = f2bf(x1 * co - x2 * si);
    Ko[base + 64] = f2bf(x2 * co + x1 * si);
  } else {                        // V heads, copy
    int idx = p - 1280;
#pragma unroll
    for (int t = 0; t < 2; t++) {
      int c = 2560 + t * 256 + idx;
      int hd = c - 2560;
      int h = hd >> 7, d = hd & 127;
      Vo[((size_t)token * NKV + h) * HDIM + d] = f2bf(conv1(c));
    }
  }
}

// ---------------- V transpose: Vb[b*S+s][kvh][d] -> Vt[(b*NKV+kvh)*128 + d][s] ----------------
__global__ __launch_bounds__(256) void transpose_v(const ushort* __restrict__ Vb,
                                                   ushort* __restrict__ Vt) {
  __shared__ ushort t[64][65];
  const int tid = threadIdx.x;
  const int s0 = blockIdx.x * 64, d0 = blockIdx.y * 64;
  const int g = blockIdx.z;                       // b*NKV + kvh
  const int b = g >> 2, kvh = g & 3;
#pragma unroll
  for (int p = 0; p < 8; p++) {
    int idx = p * 256 + tid;                      // [0,2048)
    int r = idx >> 5, c2 = (idx & 31) * 2;
    ushort2 v = *(const ushort2*)&Vb[((size_t)(b * S_LEN + s0 + r) * NKV + kvh) * HDIM + d0 + c2];
    t[r][c2] = v.x; t[r][c2 + 1] = v.y;
  }
  __syncthreads();
#pragma unroll
  for (int p = 0; p < 8; p++) {
    int idx = p * 256 + tid;
    int dr = idx >> 5, sc2 = (idx & 31) * 2;
    ushort2 v; v.x = t[sc2][dr]; v.y = t[sc2 + 1][dr];
    *(ushort2*)&Vt[((size_t)g * HDIM + d0 + dr) * S_LEN + s0 + sc2] = v;
  }
}

// ---------------- causal GQA flash attention ----------------
// grid: (B*NKV, S/16). Block = 4 waves = the 4 q-heads sharing one kv-head.
// Swapped QK^T (lane = q), log2-domain online softmax with defer-rescale,
// mask-free fast path for interior tiles, setprio around MFMA clusters.
__global__ __launch_bounds__(256, 4) void attn(
    const ushort* __restrict__ Q, const ushort* __restrict__ K,
    const ushort* __restrict__ Vt, ushort* __restrict__ ctx) {
  __shared__ __align__(16) ushort Ks[2][32 * 128];   // [key][d], chunk ^= row&7
  __shared__ __align__(16) ushort Vs[2][128 * 32];   // [d][key], chunk ^= (d>>1)&3
  const int tid = threadIdx.x;
  const int wid = tid >> 6, lane = tid & 63;
  const int l15 = lane & 15, lg = lane >> 4;
  const int bkv = blockIdx.x;                   // b*NKV + kvh
  const int b = bkv >> 2, kvh = bkv & 3;
  const int h = kvh * 4 + wid;                  // wave = one q-head of the group
  const int qb = (gridDim.y - 1) - blockIdx.y;  // longest blocks dispatch first
  const int q0 = qb * 16;

  const ushort* Kbase  = K  + ((size_t)b * S_LEN * NKV + kvh) * HDIM;
  const ushort* Vtbase = Vt + (size_t)bkv * HDIM * S_LEN;

  // Q fragments (B-operand: lane l15 = q col; Q pre-scaled by QSCALE)
  short8 qf[4];
#pragma unroll
  for (int kd = 0; kd < 4; kd++)
    qf[kd] = *(const short8*)&Q[(((size_t)(b * S_LEN + q0 + l15)) * NH + h) * HDIM + kd * 32 + lg * 8];

  auto stage = [&](int tile, int bufi) {
    const int j0t = tile * 32;
#pragma unroll
    for (int p = 0; p < 2; ++p) {
      const int i = wid * 2 + p;
      {
        const int row = i * 4 + (lane >> 4);    // key row 0..31
        const int cs  = (lane & 15) ^ (row & 7);
        load_lds16(Kbase + (size_t)(j0t + row) * (NKV * HDIM) + cs * 8,
                   &Ks[bufi][i * 512]);
      }
      {
        const int d  = i * 16 + (lane >> 2);    // d row 0..127
        const int cs = (lane & 3) ^ ((d >> 1) & 3);
        load_lds16(Vtbase + (size_t)d * S_LEN + j0t + cs * 8,
                   &Vs[bufi][i * 512]);
      }
    }
  };

  f32x4 o2[8] = {};
  float m_run = -3e30f, l_run = 0.f;
  const int ntile = q0 / 32 + 1;
  const int qrow = q0 + l15;

  auto tile_body = [&](auto MASKC, int j0, int buf) {
    constexpr bool MASK = decltype(MASKC)::value;
    // ---- swapped QK^T: sa[t][r] = S2[key = j0+t*16+lg*4+r][q] (log2 domain) ----
    f32x4 sa[2] = {};
    __builtin_amdgcn_s_setprio(1);
#pragma unroll
    for (int t = 0; t < 2; ++t) {
      const int r = t * 16 + l15;
#pragma unroll
      for (int kd = 0; kd < 4; ++kd) {
        short8 kf = *(const short8*)&Ks[buf][r * 128 + (((kd * 4 + lg) ^ (r & 7)) * 8)];
        sa[t] = __builtin_amdgcn_mfma_f32_16x16x32_bf16(kf, qf[kd], sa[t], 0, 0, 0);
      }
    }
    __builtin_amdgcn_s_setprio(0);

    // ---- online softmax, log2 domain, defer-rescale ----
    float pv[2][4];
    float mx = -3e30f;
#pragma unroll
    for (int t = 0; t < 2; ++t)
#pragma unroll
      for (int r = 0; r < 4; ++r) {
        float v = sa[t][r];
        if constexpr (MASK) {
          if (j0 + t * 16 + lg * 4 + r > qrow) v = -3e30f;
        }
        pv[t][r] = v;
        mx = fmaxf(mx, v);
      }
    mx = fmaxf(mx, __shfl_xor(mx, 16));
    mx = fmaxf(mx, __shfl_xor(mx, 32));
    if (!__all(mx <= m_run + 8.f)) {            // rescale only when max grew
      const float mnew = fmaxf(m_run, mx);
      const float fac = exp2f(m_run - mnew);
      m_run = mnew;
      l_run *= fac;
#pragma unroll
      for (int dt = 0; dt < 8; ++dt)
#pragma unroll
        for (int r = 0; r < 4; ++r) o2[dt][r] *= fac;
    }
    float sum = 0.f;
#pragma unroll
    for (int t = 0; t < 2; ++t)
#pragma unroll
      for (int r = 0; r < 4; ++r) {
        float p = exp2f(pv[t][r] - m_run);      // bounded by 2^8
        pv[t][r] = p;
        sum += p;
      }
    sum += __shfl_xor(sum, 16);
    sum += __shfl_xor(sum, 32);
    l_run += sum;

    // ---- P -> PV B-frag via pack + shfl (lane needs keys lg*8..lg*8+7) ----
    unsigned pk[2][2];
#pragma unroll
    for (int t = 0; t < 2; ++t)
#pragma unroll
      for (int p = 0; p < 2; ++p)
        pk[t][p] = ((unsigned)f2bf(pv[t][2 * p + 1]) << 16) | f2bf(pv[t][2 * p]);
    union { unsigned u[4]; short8 s; } pf;
#pragma unroll
    for (int j = 0; j < 4; ++j) {
      const int src = ((lg & 1) * 2 + (j >> 1)) * 16 + l15;
      unsigned v0 = __shfl((int)pk[0][j & 1], src);
      unsigned v1 = __shfl((int)pk[1][j & 1], src);
      pf.u[j] = (lg >= 2) ? v1 : v0;
    }

    // ---- PV: O'[d][q] += Vt-frag * P-frag ----
    __builtin_amdgcn_s_setprio(1);
#pragma unroll
    for (int dt = 0; dt < 8; ++dt) {
      const int d = dt * 16 + l15;
      short8 vf = *(const short8*)&Vs[buf][d * 32 + ((lg ^ ((d >> 1) & 3)) * 8)];
      o2[dt] = __builtin_amdgcn_mfma_f32_16x16x32_bf16(vf, pf.s, o2[dt], 0, 0, 0);
    }
    __builtin_amdgcn_s_setprio(0);
  };

  stage(0, 0);
  __syncthreads();
  int buf = 0;
  for (int jt = 0; jt < ntile; ++jt) {
    if (jt + 1 < ntile) stage(jt + 1, buf ^ 1);
    if (jt < ntile - 1)
      tile_body(std::integral_constant<bool, false>{}, jt * 32, buf);
    else
      tile_body(std::integral_constant<bool, true>{}, jt * 32, buf);
    __syncthreads();   // drains staging vmcnt; protects both LDS buffers
    buf ^= 1;
  }

  // ---- write: lane = q, regs = d ----
  const float inv_l = 1.f / l_run;
  const size_t obase = (((size_t)(b * S_LEN + q0 + l15)) * NH + h) * HDIM;
#pragma unroll
  for (int dt = 0; dt < 8; ++dt) {
    ushort4 w;
    w.x = f2bf(o2[dt][0] * inv_l);
    w.y = f2bf(o2[dt][1] * inv_l);
    w.z = f2bf(o2[dt][2] * inv_l);
    w.w = f2bf(o2[dt][3] * inv_l);
    *(ushort4*)&ctx[obase + dt * 16 + lg * 4] = w;
  }
}

// ---------------- launcher ----------------
extern "C" void kernel_launch(void* const* d_in, const int* in_sizes, int n_in,
                              void* d_out, int out_size, void* d_ws, size_t ws_size,
                              hipStream_t stream) {
  const float* x      = (const float*)d_in[0];
  const float* w_in   = (const float*)d_in[1];
  const float* b_in   = (const float*)d_in[2];
  const float* conv_w = (const float*)d_in[3];
  const float* conv_b = (const float*)d_in[4];
  const float* w_out  = (const float*)d_in[5];
  const float* b_out  = (const float*)d_in[6];
  float* out = (float*)d_out;

  char* ws = (char*)d_ws;
  size_t off = 0;
  ushort* xbf  = (ushort*)(ws + off); off += (size_t)4096 * 2048 * 2;  // x bf16; later reused as ctx
  ushort* wibf = (ushort*)(ws + off); off += (size_t)3072 * 2048 * 2;
  ushort* wobf = (ushort*)(ws + off); off += (size_t)2048 * 2048 * 2;
  ushort* qkv  = (ushort*)(ws + off); off += (size_t)4096 * 3072 * 2;  // bf16; dead after conv_rope
  ushort* Qb   = (ushort*)(ws + off); off += (size_t)4096 * 16 * 128 * 2;
  ushort* Kb   = (ushort*)(ws + off); off += (size_t)4096 * 4 * 128 * 2;
  ushort* Vb   = (ushort*)(ws + off); off += (size_t)4096 * 4 * 128 * 2;
  float*  cosT = (float*)(ws + off);  off += (size_t)2048 * 64 * 4;
  float*  sinT = (float*)(ws + off);  off += (size_t)2048 * 64 * 4;
  ushort* Vtb  = (ushort*)qkv;        // alias: transposed V lives in dead qkv buffer (8 MB)

  cast_bf16<<<8192, 256, 0, stream>>>(x, xbf, 2097152);
  cast_bf16<<<6144, 256, 0, stream>>>(w_in, wibf, 1572864);
  cast_bf16<<<4096, 256, 0, stream>>>(w_out, wobf, 1048576);
  rope_table<<<512, 256, 0, stream>>>(cosT, sinT);

  gemm_bt<true><<<dim3(32, 24), 256, 0, stream>>>(xbf, wibf, b_in, qkv, 4096, 3072, 2048);
  conv_rope<<<dim3(4096, 6), 256, 0, stream>>>(qkv, conv_w, conv_b, cosT, sinT, Qb, Kb, Vb);
  transpose_v<<<dim3(32, 2, 8), 256, 0, stream>>>(Vb, Vtb);
  attn<<<dim3(8, 128), 256, 0, stream>>>(Qb, Kb, Vtb, xbf);
  gemm_bt<false><<<dim3(32, 16), 256, 0, stream>>>(xbf, wobf, b_out, out, 4096, 2048, 2048);
}

// Round 6
// 292.029 us; speedup vs baseline: 1.0931x; 1.0931x over previous
//
#include <hip/hip_runtime.h>

#define S_LEN 2048
#define BATCH 2
#define EDIM  2048
#define NH    16
#define NKV   4
#define HDIM  128
#define QKVD  3072
// ATT_SCALE * log2(e): folded into Q at conv_rope time -> scores in log2 domain
#define QSCALE 0.12751579107188777f

typedef __attribute__((ext_vector_type(8))) short short8;
typedef __attribute__((ext_vector_type(4))) float f32x4;

__device__ __forceinline__ ushort f2bf(float f) {
  union { float f; unsigned u; } un; un.f = f;
  unsigned u = un.u + 0x7fffu + ((un.u >> 16) & 1u);
  return (ushort)(u >> 16);
}
__device__ __forceinline__ float bf2f(ushort h) {
  union { unsigned u; float f; } un; un.u = ((unsigned)h) << 16;
  return un.f;
}

__device__ __forceinline__ void load_lds16(const void* g, void* l) {
  __builtin_amdgcn_global_load_lds((const __attribute__((address_space(1))) void*)g,
                                   (__attribute__((address_space(3))) void*)l,
                                   16, 0, 0);
}

// ---------------- elementwise f32 -> bf16 cast ----------------
__global__ __launch_bounds__(256) void cast_bf16(const float* __restrict__ src,
                                                 ushort* __restrict__ dst, int n4) {
  int i = blockIdx.x * 256 + threadIdx.x;
  if (i >= n4) return;
  float4 v = ((const float4*)src)[i];
  ushort4 o;
  o.x = f2bf(v.x); o.y = f2bf(v.y); o.z = f2bf(v.z); o.w = f2bf(v.w);
  ((ushort4*)dst)[i] = o;
}

// ---------------- RoPE cos/sin table: [S][64] ----------------
__global__ __launch_bounds__(256) void rope_table(float* __restrict__ cosT,
                                                  float* __restrict__ sinT) {
  int i = blockIdx.x * 256 + threadIdx.x;   // S*64 total
  int s = i >> 6, d = i & 63;
  float inv = expf(-(float)d * 0.14391156831212787f);   // 10000^(-d/64)
  float f = (float)s * inv;
  float sv, cv;
  sincosf(f, &sv, &cv);
  cosT[i] = cv;
  sinT[i] = sv;
}

// ---------------- bf16 NT GEMM: C = A * Bt^T + bias; OBF: write bf16 else f32 ----------------
// 1-D grid with XCD-aware swizzle (T1): consecutive swizzled ids within an XCD
// share the A row-panel -> L2 reuse. nwg must be divisible by 8 (768 / 512 ok).
template <bool OBF>
__global__ __launch_bounds__(256) void gemm_bt(
    const ushort* __restrict__ A, const ushort* __restrict__ Bt,
    const float* __restrict__ bias, void* __restrict__ Cv,
    int M, int N, int K) {
  __shared__ __align__(16) ushort As[128 * 32];
  __shared__ __align__(16) ushort Bs[128 * 32];
  const int tid = threadIdx.x;
  const int wid = tid >> 6, lane = tid & 63;
  const int l15 = lane & 15, lg = lane >> 4;
  const int nTn = N >> 7;
  const int cpx = gridDim.x >> 3;
  const int swz = ((int)blockIdx.x & 7) * cpx + ((int)blockIdx.x >> 3);
  const int m0 = (swz / nTn) * 128, n0 = (swz % nTn) * 128;
  const int wr = (wid >> 1) * 64, wc = (wid & 1) * 64;
  f32x4 acc[4][4] = {};

  for (int k0 = 0; k0 < K; k0 += 32) {
#pragma unroll
    for (int j = 0; j < 2; ++j) {
      const int c = j * 256 + wid * 64 + lane;           // chunk id (16B each)
      load_lds16(A + (size_t)(m0 + (c >> 2)) * K + k0 + (c & 3) * 8,
                 As + (j * 256 + wid * 64) * 8);
      load_lds16(Bt + (size_t)(n0 + (c >> 2)) * K + k0 + (c & 3) * 8,
                 Bs + (j * 256 + wid * 64) * 8);
    }
    __syncthreads();
    short8 af[4], bf[4];
#pragma unroll
    for (int i = 0; i < 4; i++) {
      af[i] = *(const short8*)&As[(wr + i * 16 + l15) * 32 + lg * 8];
      bf[i] = *(const short8*)&Bs[(wc + i * 16 + l15) * 32 + lg * 8];
    }
#pragma unroll
    for (int mi = 0; mi < 4; mi++)
#pragma unroll
      for (int ni = 0; ni < 4; ni++)
        acc[mi][ni] = __builtin_amdgcn_mfma_f32_16x16x32_bf16(af[mi], bf[ni], acc[mi][ni], 0, 0, 0);
    __syncthreads();
  }

#pragma unroll
  for (int mi = 0; mi < 4; mi++) {
#pragma unroll
    for (int ni = 0; ni < 4; ni++) {
      const int col = n0 + wc + ni * 16 + l15;
      const float bv = bias[col];
#pragma unroll
      for (int r = 0; r < 4; r++) {
        const int row = m0 + wr + mi * 16 + lg * 4 + r;
        if constexpr (OBF)
          ((ushort*)Cv)[(size_t)row * N + col] = f2bf(acc[mi][ni][r] + bv);
        else
          ((float*)Cv)[(size_t)row * N + col] = acc[mi][ni][r] + bv;
      }
    }
  }
}

// ---------------- causal depthwise conv(K=4) + bias + RoPE -> Q/K/V bf16 ----------------
// qkv is bf16. Qo is pre-scaled by QSCALE (attn works in log2 domain).
__global__ __launch_bounds__(256) void conv_rope(
    const ushort* __restrict__ qkv, const float* __restrict__ cw,
    const float* __restrict__ cb, const float* __restrict__ cosT,
    const float* __restrict__ sinT, ushort* __restrict__ Qo,
    ushort* __restrict__ Ko, ushort* __restrict__ Vo) {
  const int token = blockIdx.x;            // b*S + s
  const int s = token & (S_LEN - 1);
  const int p = blockIdx.y * 256 + threadIdx.x;   // 0..1535

  auto conv1 = [&](int c) -> float {
    float a = cb[c];
#pragma unroll
    for (int j = 0; j < 4; j++) {
      int ss = s - 3 + j;
      if (ss >= 0) a += bf2f(qkv[(size_t)(token - 3 + j) * QKVD + c]) * cw[c * 4 + j];
    }
    return a;
  };

  if (p < 1024) {                 // Q heads, RoPE pair (d, d+64); pre-scaled
    int h = p >> 6, d = p & 63;
    int c1 = h * 128 + d;
    float x1 = conv1(c1), x2 = conv1(c1 + 64);
    float co = cosT[s * 64 + d], si = sinT[s * 64 + d];
    size_t base = ((size_t)token * NH + h) * HDIM + d;
    Qo[base]      = f2bf((x1 * co - x2 * si) * QSCALE);
    Qo[base + 64] = f2bf((x2 * co + x1 * si) * QSCALE);
  } else if (p < 1280) {          // K heads, RoPE pair
    int idx = p - 1024;
    int h = idx >> 6, d = idx & 63;
    int c1 = 2048 + h * 128 + d;
    float x1 = conv1(c1), x2 = conv1(c1 + 64);
    float co = cosT[s * 64 + d], si = sinT[s * 64 + d];
    size_t base = ((size_t)token * NKV + h) * HDIM + d;
    Ko[base]      = f2bf(x1 * co - x2 * si);
    Ko[base + 64] = f2bf(x2 * co + x1 * si);
  } else {                        // V heads, copy
    int idx = p - 1280;
#pragma unroll
    for (int t = 0; t < 2; t++) {
      int c = 2560 + t * 256 + idx;
      int hd = c - 2560;
      int h = hd >> 7, d = hd & 127;
      Vo[((size_t)token * NKV + h) * HDIM + d] = f2bf(conv1(c));
    }
  }
}

// ---------------- V transpose: Vb[b*S+s][kvh][d] -> Vt[(b*NKV+kvh)*128 + d][s] ----------------
__global__ __launch_bounds__(256) void transpose_v(const ushort* __restrict__ Vb,
                                                   ushort* __restrict__ Vt) {
  __shared__ ushort t[64][65];
  const int tid = threadIdx.x;
  const int s0 = blockIdx.x * 64, d0 = blockIdx.y * 64;
  const int g = blockIdx.z;                       // b*NKV + kvh
  const int b = g >> 2, kvh = g & 3;
#pragma unroll
  for (int p = 0; p < 8; p++) {
    int idx = p * 256 + tid;                      // [0,2048)
    int r = idx >> 5, c2 = (idx & 31) * 2;
    ushort2 v = *(const ushort2*)&Vb[((size_t)(b * S_LEN + s0 + r) * NKV + kvh) * HDIM + d0 + c2];
    t[r][c2] = v.x; t[r][c2 + 1] = v.y;
  }
  __syncthreads();
#pragma unroll
  for (int p = 0; p < 8; p++) {
    int idx = p * 256 + tid;
    int dr = idx >> 5, sc2 = (idx & 31) * 2;
    ushort2 v; v.x = t[sc2][dr]; v.y = t[sc2 + 1][dr];
    *(ushort2*)&Vt[((size_t)g * HDIM + d0 + dr) * S_LEN + s0 + sc2] = v;
  }
}

// ---------------- causal GQA flash attention (round-4 structure, log2 domain) ----------------
// grid: (B*NKV, S/16). Block = 4 waves = the 4 q-heads sharing one kv-head.
// Swapped QK^T (lane = q), in-register softmax, P via pack+shfl, no setprio,
// unconditional rescale (keeps o2 live-range branch-free -> no spill).
__global__ __launch_bounds__(256, 4) void attn(
    const ushort* __restrict__ Q, const ushort* __restrict__ K,
    const ushort* __restrict__ Vt, ushort* __restrict__ ctx) {
  __shared__ __align__(16) ushort Ks[2][32 * 128];   // [key][d], chunk ^= row&7
  __shared__ __align__(16) ushort Vs[2][128 * 32];   // [d][key], chunk ^= (d>>1)&3
  const int tid = threadIdx.x;
  const int wid = tid >> 6, lane = tid & 63;
  const int l15 = lane & 15, lg = lane >> 4;
  const int bkv = blockIdx.x;                   // b*NKV + kvh; id%8 = bkv -> one XCD per bkv
  const int b = bkv >> 2, kvh = bkv & 3;
  const int h = kvh * 4 + wid;                  // wave = one q-head of the group
  const int qb = (gridDim.y - 1) - blockIdx.y;  // longest blocks dispatch first
  const int q0 = qb * 16;

  const ushort* Kbase  = K  + ((size_t)b * S_LEN * NKV + kvh) * HDIM;
  const ushort* Vtbase = Vt + (size_t)bkv * HDIM * S_LEN;

  // Q fragments (B-operand: lane l15 = q col; Q pre-scaled by QSCALE)
  short8 qf[4];
#pragma unroll
  for (int kd = 0; kd < 4; kd++)
    qf[kd] = *(const short8*)&Q[(((size_t)(b * S_LEN + q0 + l15)) * NH + h) * HDIM + kd * 32 + lg * 8];

  auto stage = [&](int tile, int bufi) {
    const int j0t = tile * 32;
#pragma unroll
    for (int p = 0; p < 2; ++p) {
      const int i = wid * 2 + p;
      {
        const int row = i * 4 + (lane >> 4);    // key row 0..31
        const int cs  = (lane & 15) ^ (row & 7);
        load_lds16(Kbase + (size_t)(j0t + row) * (NKV * HDIM) + cs * 8,
                   &Ks[bufi][i * 512]);
      }
      {
        const int d  = i * 16 + (lane >> 2);    // d row 0..127
        const int cs = (lane & 3) ^ ((d >> 1) & 3);
        load_lds16(Vtbase + (size_t)d * S_LEN + j0t + cs * 8,
                   &Vs[bufi][i * 512]);
      }
    }
  };

  f32x4 o2[8] = {};
  float m_run = -3e30f, l_run = 0.f;
  const int ntile = q0 / 32 + 1;
  const int qrow = q0 + l15;

  stage(0, 0);
  __syncthreads();
  int buf = 0;
  for (int jt = 0; jt < ntile; ++jt) {
    const int j0 = jt * 32;
    if (jt + 1 < ntile) stage(jt + 1, buf ^ 1);

    // ---- swapped QK^T: sa[t][r] = S2[key = j0+t*16+lg*4+r][q] (log2 domain) ----
    f32x4 sa[2] = {};
#pragma unroll
    for (int t = 0; t < 2; ++t) {
      const int r = t * 16 + l15;
#pragma unroll
      for (int kd = 0; kd < 4; ++kd) {
        short8 kf = *(const short8*)&Ks[buf][r * 128 + (((kd * 4 + lg) ^ (r & 7)) * 8)];
        sa[t] = __builtin_amdgcn_mfma_f32_16x16x32_bf16(kf, qf[kd], sa[t], 0, 0, 0);
      }
    }

    // ---- in-register online softmax (lane = q; scores already log2-scaled) ----
    float pv[2][4];
    float mx = -3e30f;
#pragma unroll
    for (int t = 0; t < 2; ++t)
#pragma unroll
      for (int r = 0; r < 4; ++r) {
        float v = sa[t][r];
        if (j0 + t * 16 + lg * 4 + r > qrow) v = -3e30f;   // causal mask
        pv[t][r] = v;
        mx = fmaxf(mx, v);
      }
    mx = fmaxf(mx, __shfl_xor(mx, 16));
    mx = fmaxf(mx, __shfl_xor(mx, 32));
    const float mnew = fmaxf(m_run, mx);
    float sum = 0.f;
#pragma unroll
    for (int t = 0; t < 2; ++t)
#pragma unroll
      for (int r = 0; r < 4; ++r) {
        float p = exp2f(pv[t][r] - mnew);
        pv[t][r] = p;
        sum += p;
      }
    sum += __shfl_xor(sum, 16);
    sum += __shfl_xor(sum, 32);
    const float fac = exp2f(m_run - mnew);
    m_run = mnew;
    l_run = l_run * fac + sum;
#pragma unroll
    for (int dt = 0; dt < 8; ++dt)
#pragma unroll
      for (int r = 0; r < 4; ++r) o2[dt][r] *= fac;

    // ---- P -> PV B-frag via pack + shfl (lane needs keys lg*8..lg*8+7) ----
    unsigned pk[2][2];
#pragma unroll
    for (int t = 0; t < 2; ++t)
#pragma unroll
      for (int p = 0; p < 2; ++p)
        pk[t][p] = ((unsigned)f2bf(pv[t][2 * p + 1]) << 16) | f2bf(pv[t][2 * p]);
    union { unsigned u[4]; short8 s; } pf;
#pragma unroll
    for (int j = 0; j < 4; ++j) {
      const int src = ((lg & 1) * 2 + (j >> 1)) * 16 + l15;
      unsigned v0 = __shfl((int)pk[0][j & 1], src);
      unsigned v1 = __shfl((int)pk[1][j & 1], src);
      pf.u[j] = (lg >= 2) ? v1 : v0;
    }

    // ---- PV: O'[d][q] += Vt-frag * P-frag ----
#pragma unroll
    for (int dt = 0; dt < 8; ++dt) {
      const int d = dt * 16 + l15;
      short8 vf = *(const short8*)&Vs[buf][d * 32 + ((lg ^ ((d >> 1) & 3)) * 8)];
      o2[dt] = __builtin_amdgcn_mfma_f32_16x16x32_bf16(vf, pf.s, o2[dt], 0, 0, 0);
    }

    __syncthreads();   // drains staging vmcnt; protects both LDS buffers
    buf ^= 1;
  }

  // ---- write: lane = q, regs = d ----
  const float inv_l = 1.f / l_run;
  const size_t obase = (((size_t)(b * S_LEN + q0 + l15)) * NH + h) * HDIM;
#pragma unroll
  for (int dt = 0; dt < 8; ++dt) {
    ushort4 w;
    w.x = f2bf(o2[dt][0] * inv_l);
    w.y = f2bf(o2[dt][1] * inv_l);
    w.z = f2bf(o2[dt][2] * inv_l);
    w.w = f2bf(o2[dt][3] * inv_l);
    *(ushort4*)&ctx[obase + dt * 16 + lg * 4] = w;
  }
}

// ---------------- launcher ----------------
extern "C" void kernel_launch(void* const* d_in, const int* in_sizes, int n_in,
                              void* d_out, int out_size, void* d_ws, size_t ws_size,
                              hipStream_t stream) {
  const float* x      = (const float*)d_in[0];
  const float* w_in   = (const float*)d_in[1];
  const float* b_in   = (const float*)d_in[2];
  const float* conv_w = (const float*)d_in[3];
  const float* conv_b = (const float*)d_in[4];
  const float* w_out  = (const float*)d_in[5];
  const float* b_out  = (const float*)d_in[6];
  float* out = (float*)d_out;

  char* ws = (char*)d_ws;
  size_t off = 0;
  ushort* xbf  = (ushort*)(ws + off); off += (size_t)4096 * 2048 * 2;  // x bf16; later reused as ctx
  ushort* wibf = (ushort*)(ws + off); off += (size_t)3072 * 2048 * 2;
  ushort* wobf = (ushort*)(ws + off); off += (size_t)2048 * 2048 * 2;
  ushort* qkv  = (ushort*)(ws + off); off += (size_t)4096 * 3072 * 2;  // bf16; dead after conv_rope
  ushort* Qb   = (ushort*)(ws + off); off += (size_t)4096 * 16 * 128 * 2;
  ushort* Kb   = (ushort*)(ws + off); off += (size_t)4096 * 4 * 128 * 2;
  ushort* Vb   = (ushort*)(ws + off); off += (size_t)4096 * 4 * 128 * 2;
  float*  cosT = (float*)(ws + off);  off += (size_t)2048 * 64 * 4;
  float*  sinT = (float*)(ws + off);  off += (size_t)2048 * 64 * 4;
  ushort* Vtb  = (ushort*)qkv;        // alias: transposed V lives in dead qkv buffer (8 MB)

  cast_bf16<<<8192, 256, 0, stream>>>(x, xbf, 2097152);
  cast_bf16<<<6144, 256, 0, stream>>>(w_in, wibf, 1572864);
  cast_bf16<<<4096, 256, 0, stream>>>(w_out, wobf, 1048576);
  rope_table<<<512, 256, 0, stream>>>(cosT, sinT);

  gemm_bt<true><<<768, 256, 0, stream>>>(xbf, wibf, b_in, qkv, 4096, 3072, 2048);
  conv_rope<<<dim3(4096, 6), 256, 0, stream>>>(qkv, conv_w, conv_b, cosT, sinT, Qb, Kb, Vb);
  transpose_v<<<dim3(32, 2, 8), 256, 0, stream>>>(Vb, Vtb);
  attn<<<dim3(8, 128), 256, 0, stream>>>(Qb, Kb, Vtb, xbf);
  gemm_bt<false><<<512, 256, 0, stream>>>(xbf, wobf, b_out, out, 4096, 2048, 2048);
}

// Round 7
// 274.708 us; speedup vs baseline: 1.1620x; 1.0630x over previous
//
#include <hip/hip_runtime.h>

#define S_LEN 2048
#define BATCH 2
#define EDIM  2048
#define NH    16
#define NKV   4
#define HDIM  128
#define QKVD  3072
// ATT_SCALE * log2(e): folded into Q at conv_rope time -> scores in log2 domain
#define QSCALE 0.12751579107188777f

typedef __attribute__((ext_vector_type(8))) short short8;
typedef __attribute__((ext_vector_type(4))) float f32x4;

__device__ __forceinline__ ushort f2bf(float f) {
  union { float f; unsigned u; } un; un.f = f;
  unsigned u = un.u + 0x7fffu + ((un.u >> 16) & 1u);
  return (ushort)(u >> 16);
}
__device__ __forceinline__ float bf2f(ushort h) {
  union { unsigned u; float f; } un; un.u = ((unsigned)h) << 16;
  return un.f;
}
// packed bf16 convert: low16 = bf16(lo), high16 = bf16(hi), RNE
__device__ __forceinline__ unsigned cvt_pk_bf16(float lo, float hi) {
  unsigned r;
  asm("v_cvt_pk_bf16_f32 %0, %1, %2" : "=v"(r) : "v"(lo), "v"(hi));
  return r;
}
__device__ __forceinline__ float fexp2(float x) { return __builtin_amdgcn_exp2f(x); }

__device__ __forceinline__ void load_lds16(const void* g, void* l) {
  __builtin_amdgcn_global_load_lds((const __attribute__((address_space(1))) void*)g,
                                   (__attribute__((address_space(3))) void*)l,
                                   16, 0, 0);
}

// ---------------- elementwise f32 -> bf16 cast ----------------
__global__ __launch_bounds__(256) void cast_bf16(const float* __restrict__ src,
                                                 ushort* __restrict__ dst, int n4) {
  int i = blockIdx.x * 256 + threadIdx.x;
  if (i >= n4) return;
  float4 v = ((const float4*)src)[i];
  ushort4 o;
  o.x = f2bf(v.x); o.y = f2bf(v.y); o.z = f2bf(v.z); o.w = f2bf(v.w);
  ((ushort4*)dst)[i] = o;
}

// ---------------- RoPE cos/sin table: [S][64] ----------------
__global__ __launch_bounds__(256) void rope_table(float* __restrict__ cosT,
                                                  float* __restrict__ sinT) {
  int i = blockIdx.x * 256 + threadIdx.x;   // S*64 total
  int s = i >> 6, d = i & 63;
  float inv = expf(-(float)d * 0.14391156831212787f);   // 10000^(-d/64)
  float f = (float)s * inv;
  float sv, cv;
  sincosf(f, &sv, &cv);
  cosT[i] = cv;
  sinT[i] = sv;
}

// ---------------- bf16 NT GEMM: C = A * Bt^T + bias; OBF: write bf16 else f32 ----------------
// 1-D grid with XCD-aware swizzle (T1). nwg divisible by 8 (768 / 512 ok).
template <bool OBF>
__global__ __launch_bounds__(256) void gemm_bt(
    const ushort* __restrict__ A, const ushort* __restrict__ Bt,
    const float* __restrict__ bias, void* __restrict__ Cv,
    int M, int N, int K) {
  __shared__ __align__(16) ushort As[128 * 32];
  __shared__ __align__(16) ushort Bs[128 * 32];
  const int tid = threadIdx.x;
  const int wid = tid >> 6, lane = tid & 63;
  const int l15 = lane & 15, lg = lane >> 4;
  const int nTn = N >> 7;
  const int cpx = gridDim.x >> 3;
  const int swz = ((int)blockIdx.x & 7) * cpx + ((int)blockIdx.x >> 3);
  const int m0 = (swz / nTn) * 128, n0 = (swz % nTn) * 128;
  const int wr = (wid >> 1) * 64, wc = (wid & 1) * 64;
  f32x4 acc[4][4] = {};

  for (int k0 = 0; k0 < K; k0 += 32) {
#pragma unroll
    for (int j = 0; j < 2; ++j) {
      const int c = j * 256 + wid * 64 + lane;           // chunk id (16B each)
      load_lds16(A + (size_t)(m0 + (c >> 2)) * K + k0 + (c & 3) * 8,
                 As + (j * 256 + wid * 64) * 8);
      load_lds16(Bt + (size_t)(n0 + (c >> 2)) * K + k0 + (c & 3) * 8,
                 Bs + (j * 256 + wid * 64) * 8);
    }
    __syncthreads();
    short8 af[4], bf[4];
#pragma unroll
    for (int i = 0; i < 4; i++) {
      af[i] = *(const short8*)&As[(wr + i * 16 + l15) * 32 + lg * 8];
      bf[i] = *(const short8*)&Bs[(wc + i * 16 + l15) * 32 + lg * 8];
    }
#pragma unroll
    for (int mi = 0; mi < 4; mi++)
#pragma unroll
      for (int ni = 0; ni < 4; ni++)
        acc[mi][ni] = __builtin_amdgcn_mfma_f32_16x16x32_bf16(af[mi], bf[ni], acc[mi][ni], 0, 0, 0);
    __syncthreads();
  }

#pragma unroll
  for (int mi = 0; mi < 4; mi++) {
#pragma unroll
    for (int ni = 0; ni < 4; ni++) {
      const int col = n0 + wc + ni * 16 + l15;
      const float bv = bias[col];
#pragma unroll
      for (int r = 0; r < 4; r++) {
        const int row = m0 + wr + mi * 16 + lg * 4 + r;
        if constexpr (OBF)
          ((ushort*)Cv)[(size_t)row * N + col] = f2bf(acc[mi][ni][r] + bv);
        else
          ((float*)Cv)[(size_t)row * N + col] = acc[mi][ni][r] + bv;
      }
    }
  }
}

// ---------------- causal depthwise conv(K=4) + bias + RoPE -> Q/K/V bf16 ----------------
__global__ __launch_bounds__(256) void conv_rope(
    const ushort* __restrict__ qkv, const float* __restrict__ cw,
    const float* __restrict__ cb, const float* __restrict__ cosT,
    const float* __restrict__ sinT, ushort* __restrict__ Qo,
    ushort* __restrict__ Ko, ushort* __restrict__ Vo) {
  const int token = blockIdx.x;            // b*S + s
  const int s = token & (S_LEN - 1);
  const int p = blockIdx.y * 256 + threadIdx.x;   // 0..1535

  auto conv1 = [&](int c) -> float {
    float a = cb[c];
#pragma unroll
    for (int j = 0; j < 4; j++) {
      int ss = s - 3 + j;
      if (ss >= 0) a += bf2f(qkv[(size_t)(token - 3 + j) * QKVD + c]) * cw[c * 4 + j];
    }
    return a;
  };

  if (p < 1024) {                 // Q heads, RoPE pair (d, d+64); pre-scaled
    int h = p >> 6, d = p & 63;
    int c1 = h * 128 + d;
    float x1 = conv1(c1), x2 = conv1(c1 + 64);
    float co = cosT[s * 64 + d], si = sinT[s * 64 + d];
    size_t base = ((size_t)token * NH + h) * HDIM + d;
    Qo[base]      = f2bf((x1 * co - x2 * si) * QSCALE);
    Qo[base + 64] = f2bf((x2 * co + x1 * si) * QSCALE);
  } else if (p < 1280) {          // K heads, RoPE pair
    int idx = p - 1024;
    int h = idx >> 6, d = idx & 63;
    int c1 = 2048 + h * 128 + d;
    float x1 = conv1(c1), x2 = conv1(c1 + 64);
    float co = cosT[s * 64 + d], si = sinT[s * 64 + d];
    size_t base = ((size_t)token * NKV + h) * HDIM + d;
    Ko[base]      = f2bf(x1 * co - x2 * si);
    Ko[base + 64] = f2bf(x2 * co + x1 * si);
  } else {                        // V heads, copy
    int idx = p - 1280;
#pragma unroll
    for (int t = 0; t < 2; t++) {
      int c = 2560 + t * 256 + idx;
      int hd = c - 2560;
      int h = hd >> 7, d = hd & 127;
      Vo[((size_t)token * NKV + h) * HDIM + d] = f2bf(conv1(c));
    }
  }
}

// ---------------- V transpose: Vb[b*S+s][kvh][d] -> Vt[(b*NKV+kvh)*128 + d][s] ----------------
__global__ __launch_bounds__(256) void transpose_v(const ushort* __restrict__ Vb,
                                                   ushort* __restrict__ Vt) {
  __shared__ ushort t[64][65];
  const int tid = threadIdx.x;
  const int s0 = blockIdx.x * 64, d0 = blockIdx.y * 64;
  const int g = blockIdx.z;                       // b*NKV + kvh
  const int b = g >> 2, kvh = g & 3;
#pragma unroll
  for (int p = 0; p < 8; p++) {
    int idx = p * 256 + tid;                      // [0,2048)
    int r = idx >> 5, c2 = (idx & 31) * 2;
    ushort2 v = *(const ushort2*)&Vb[((size_t)(b * S_LEN + s0 + r) * NKV + kvh) * HDIM + d0 + c2];
    t[r][c2] = v.x; t[r][c2 + 1] = v.y;
  }
  __syncthreads();
#pragma unroll
  for (int p = 0; p < 8; p++) {
    int idx = p * 256 + tid;
    int dr = idx >> 5, sc2 = (idx & 31) * 2;
    ushort2 v; v.x = t[sc2][dr]; v.y = t[sc2 + 1][dr];
    *(ushort2*)&Vt[((size_t)g * HDIM + d0 + dr) * S_LEN + s0 + sc2] = v;
  }
}

// ---------------- causal GQA flash attention, 64-key tiles ----------------
// grid: (B*NKV, S/16). Block = 4 waves = the 4 q-heads sharing one kv-head.
// Swapped QK^T (lane = q), log2-domain in-register softmax (v_exp native),
// P-pack via v_cvt_pk_bf16_f32, P redistribution via shfl. 64 KB LDS dbuf.
__global__ __launch_bounds__(256, 2) void attn(
    const ushort* __restrict__ Q, const ushort* __restrict__ K,
    const ushort* __restrict__ Vt, ushort* __restrict__ ctx) {
  __shared__ __align__(16) ushort Ks[2][64 * 128];   // [key][d], chunk(16) ^= row&7
  __shared__ __align__(16) ushort Vs[2][128 * 64];   // [d][key], chunk(8)  ^= d&7
  const int tid = threadIdx.x;
  const int wid = tid >> 6, lane = tid & 63;
  const int l15 = lane & 15, lg = lane >> 4;
  const int bkv = blockIdx.x;                   // b*NKV + kvh; maps 1:1 to an XCD
  const int b = bkv >> 2, kvh = bkv & 3;
  const int h = kvh * 4 + wid;                  // wave = one q-head of the group
  const int qb = (gridDim.y - 1) - blockIdx.y;  // longest blocks dispatch first
  const int q0 = qb * 16;

  const ushort* Kbase  = K  + ((size_t)b * S_LEN * NKV + kvh) * HDIM;
  const ushort* Vtbase = Vt + (size_t)bkv * HDIM * S_LEN;

  // Q fragments (B-operand: lane l15 = q col; Q pre-scaled by QSCALE)
  short8 qf[4];
#pragma unroll
  for (int kd = 0; kd < 4; kd++)
    qf[kd] = *(const short8*)&Q[(((size_t)(b * S_LEN + q0 + l15)) * NH + h) * HDIM + kd * 32 + lg * 8];

  // stage one 64-key tile: K 16KB + Vt 16KB, 4+4 wave-instrs per wave
  auto stage = [&](int tile, int bufi) {
    const int j0t = tile * 64;
#pragma unroll
    for (int p = 0; p < 4; ++p) {
      const int i = wid * 4 + p;                // 0..15
      {
        const int row = i * 4 + (lane >> 4);    // key row 0..63
        const int cs  = (lane & 15) ^ (row & 7);
        load_lds16(Kbase + (size_t)(j0t + row) * (NKV * HDIM) + cs * 8,
                   &Ks[bufi][i * 512]);
      }
      {
        const int d  = i * 8 + (lane >> 3);     // d row 0..127
        const int cs = (lane & 7) ^ (d & 7);
        load_lds16(Vtbase + (size_t)d * S_LEN + j0t + cs * 8,
                   &Vs[bufi][i * 512]);
      }
    }
  };

  f32x4 o2[8] = {};
  float m_run = -3e30f, l_run = 0.f;
  const int ntile = q0 / 64 + 1;
  const int qrow = q0 + l15;

  stage(0, 0);
  __syncthreads();
  int buf = 0;
  for (int jt = 0; jt < ntile; ++jt) {
    const int j0 = jt * 64;
    if (jt + 1 < ntile) stage(jt + 1, buf ^ 1);

    // ---- swapped QK^T: sa[t][r] = S2[key = j0+t*16+lg*4+r][q] (log2 domain) ----
    f32x4 sa[4] = {};
#pragma unroll
    for (int t = 0; t < 4; ++t) {
      const int r = t * 16 + l15;
#pragma unroll
      for (int kd = 0; kd < 4; ++kd) {
        short8 kf = *(const short8*)&Ks[buf][r * 128 + (((kd * 4 + lg) ^ (r & 7)) * 8)];
        sa[t] = __builtin_amdgcn_mfma_f32_16x16x32_bf16(kf, qf[kd], sa[t], 0, 0, 0);
      }
    }

    // ---- in-register online softmax over 16 scores (lane = q) ----
    float pv[4][4];
    float mx = -3e30f;
#pragma unroll
    for (int t = 0; t < 4; ++t)
#pragma unroll
      for (int r = 0; r < 4; ++r) {
        float v = sa[t][r];
        if (j0 + t * 16 + lg * 4 + r > qrow) v = -3e30f;   // causal mask
        pv[t][r] = v;
        mx = fmaxf(mx, v);
      }
    mx = fmaxf(mx, __shfl_xor(mx, 16));
    mx = fmaxf(mx, __shfl_xor(mx, 32));
    const float mnew = fmaxf(m_run, mx);
    float sum = 0.f;
#pragma unroll
    for (int t = 0; t < 4; ++t)
#pragma unroll
      for (int r = 0; r < 4; ++r) {
        float p = fexp2(pv[t][r] - mnew);
        pv[t][r] = p;
        sum += p;
      }
    sum += __shfl_xor(sum, 16);
    sum += __shfl_xor(sum, 32);
    const float fac = fexp2(m_run - mnew);
    m_run = mnew;
    l_run = l_run * fac + sum;
#pragma unroll
    for (int dt = 0; dt < 8; ++dt)
#pragma unroll
      for (int r = 0; r < 4; ++r) o2[dt][r] *= fac;

    // ---- P -> bf16 (cvt_pk) -> PV B-frags via shfl ----
    unsigned pk[4][2];
#pragma unroll
    for (int t = 0; t < 4; ++t)
#pragma unroll
      for (int p = 0; p < 2; ++p)
        pk[t][p] = cvt_pk_bf16(pv[t][2 * p], pv[t][2 * p + 1]);

    union U8 { unsigned u[4]; short8 s; } pfk[2];
#pragma unroll
    for (int ks = 0; ks < 2; ++ks)
#pragma unroll
      for (int j = 0; j < 4; ++j) {
        const int src = ((lg & 1) * 2 + (j >> 1)) * 16 + l15;
        unsigned v0 = __shfl((int)pk[ks * 2][j & 1], src);
        unsigned v1 = __shfl((int)pk[ks * 2 + 1][j & 1], src);
        pfk[ks].u[j] = (lg >= 2) ? v1 : v0;
      }

    // ---- PV: O'[d][q] += Vt-frag * P-frag (two K=32 slots) ----
#pragma unroll
    for (int dt = 0; dt < 8; ++dt) {
      const int d = dt * 16 + l15;
#pragma unroll
      for (int ks = 0; ks < 2; ++ks) {
        short8 vf = *(const short8*)&Vs[buf][d * 64 + (((ks * 4 + lg) ^ (d & 7)) * 8)];
        o2[dt] = __builtin_amdgcn_mfma_f32_16x16x32_bf16(vf, pfk[ks].s, o2[dt], 0, 0, 0);
      }
    }

    __syncthreads();   // drains staging vmcnt; protects both LDS buffers
    buf ^= 1;
  }

  // ---- write: lane = q, regs = d ----
  const float inv_l = 1.f / l_run;
  const size_t obase = (((size_t)(b * S_LEN + q0 + l15)) * NH + h) * HDIM;
#pragma unroll
  for (int dt = 0; dt < 8; ++dt) {
    ushort4 w;
    w.x = f2bf(o2[dt][0] * inv_l);
    w.y = f2bf(o2[dt][1] * inv_l);
    w.z = f2bf(o2[dt][2] * inv_l);
    w.w = f2bf(o2[dt][3] * inv_l);
    *(ushort4*)&ctx[obase + dt * 16 + lg * 4] = w;
  }
}

// ---------------- launcher ----------------
extern "C" void kernel_launch(void* const* d_in, const int* in_sizes, int n_in,
                              void* d_out, int out_size, void* d_ws, size_t ws_size,
                              hipStream_t stream) {
  const float* x      = (const float*)d_in[0];
  const float* w_in   = (const float*)d_in[1];
  const float* b_in   = (const float*)d_in[2];
  const float* conv_w = (const float*)d_in[3];
  const float* conv_b = (const float*)d_in[4];
  const float* w_out  = (const float*)d_in[5];
  const float* b_out  = (const float*)d_in[6];
  float* out = (float*)d_out;

  char* ws = (char*)d_ws;
  size_t off = 0;
  ushort* xbf  = (ushort*)(ws + off); off += (size_t)4096 * 2048 * 2;  // x bf16; later reused as ctx
  ushort* wibf = (ushort*)(ws + off); off += (size_t)3072 * 2048 * 2;
  ushort* wobf = (ushort*)(ws + off); off += (size_t)2048 * 2048 * 2;
  ushort* qkv  = (ushort*)(ws + off); off += (size_t)4096 * 3072 * 2;  // bf16; dead after conv_rope
  ushort* Qb   = (ushort*)(ws + off); off += (size_t)4096 * 16 * 128 * 2;
  ushort* Kb   = (ushort*)(ws + off); off += (size_t)4096 * 4 * 128 * 2;
  ushort* Vb   = (ushort*)(ws + off); off += (size_t)4096 * 4 * 128 * 2;
  float*  cosT = (float*)(ws + off);  off += (size_t)2048 * 64 * 4;
  float*  sinT = (float*)(ws + off);  off += (size_t)2048 * 64 * 4;
  ushort* Vtb  = (ushort*)qkv;        // alias: transposed V lives in dead qkv buffer (8 MB)

  cast_bf16<<<8192, 256, 0, stream>>>(x, xbf, 2097152);
  cast_bf16<<<6144, 256, 0, stream>>>(w_in, wibf, 1572864);
  cast_bf16<<<4096, 256, 0, stream>>>(w_out, wobf, 1048576);
  rope_table<<<512, 256, 0, stream>>>(cosT, sinT);

  gemm_bt<true><<<768, 256, 0, stream>>>(xbf, wibf, b_in, qkv, 4096, 3072, 2048);
  conv_rope<<<dim3(4096, 6), 256, 0, stream>>>(qkv, conv_w, conv_b, cosT, sinT, Qb, Kb, Vb);
  transpose_v<<<dim3(32, 2, 8), 256, 0, stream>>>(Vb, Vtb);
  attn<<<dim3(8, 128), 256, 0, stream>>>(Qb, Kb, Vtb, xbf);
  gemm_bt<false><<<512, 256, 0, stream>>>(xbf, wobf, b_out, out, 4096, 2048, 2048);
}